// Round 1
// 1153.061 us; speedup vs baseline: 1.0027x; 1.0027x over previous
//
#include <hip/hip_runtime.h>
#include <stdint.h>

typedef __bf16 bf16;
typedef __bf16 bf16x8 __attribute__((ext_vector_type(8)));
typedef float floatx4 __attribute__((ext_vector_type(4)));

#define LOG2E 1.44269504088896340736f

// ---------------- async global->LDS (16B/lane, wave-uniform LDS base) ----------------
__device__ __forceinline__ void gl2lds16(const bf16* g, bf16* l) {
    __builtin_amdgcn_global_load_lds((__attribute__((address_space(1))) void*)g,
                                     (__attribute__((address_space(3))) void*)l,
                                     16, 0, 0);
}

// chunk swizzle (16B chunks): spreads row-strided b128 reads across all 32 banks
template<int COLS>
__device__ __forceinline__ int swz(int ch, int r) {
    if constexpr (COLS == 32) return ch ^ ((r >> 1) & 3);
    else                      return ch ^ (r & 7);
}

// Stage ROWS x COLS bf16 tile into LDS, lane-contiguous dest, source chunk-swizzled.
template<int ROWS, int COLS>
__device__ __forceinline__ void stage_tile_sw(bf16* lds, const bf16* g, int srcStride, int wave, int lane) {
    constexpr int NINST = (ROWS * COLS * 2) / 1024;
    constexpr int ROWB  = COLS * 2;
    #pragma unroll
    for (int u = 0; u < NINST / 4; ++u) {
        int t  = wave + u * 4;
        int ob = t * 1024 + lane * 16;
        int r  = ob / ROWB;
        int ch = (ob % ROWB) >> 4;
        int sc = swz<COLS>(ch, r);
        gl2lds16(g + r * srcStride + sc * 8, lds + t * 512);
    }
}

// ---------------- 128x128 bf16 GEMM core: C[M,N] = A[M,K] * Bt[N,K]^T ----------------
template<int RELU, int OUTF, int OUTB>
__device__ __forceinline__ void gemm_core(const bf16* __restrict__ A, const bf16* __restrict__ Bt,
                                          const float* __restrict__ bias, float scale,
                                          float* __restrict__ outf, bf16* __restrict__ outb,
                                          int M, int N, int K, int m0, int n0) {
    __shared__ bf16 As[128 * 32];
    __shared__ bf16 Bs[128 * 32];
    const int tid = threadIdx.x, wave = tid >> 6, lane = tid & 63;
    const int wr = wave >> 1, wc = wave & 1;
    const int quad = lane >> 4, lq = lane & 15;
    const int swa = quad ^ ((lq >> 1) & 3);

    floatx4 acc[4][4] = {};
    const bf16* Ap = A + (size_t)m0 * K;
    const bf16* Bp = Bt + (size_t)n0 * K;

    for (int k0 = 0; k0 < K; k0 += 32) {
        stage_tile_sw<128, 32>(As, Ap + k0, K, wave, lane);
        stage_tile_sw<128, 32>(Bs, Bp + k0, K, wave, lane);
        __syncthreads();
        bf16x8 af[4], bfr[4];
        #pragma unroll
        for (int i = 0; i < 4; i++)
            af[i] = *(const bf16x8*)&As[(wr * 64 + i * 16 + lq) * 32 + swa * 8];
        #pragma unroll
        for (int j = 0; j < 4; j++)
            bfr[j] = *(const bf16x8*)&Bs[(wc * 64 + j * 16 + lq) * 32 + swa * 8];
        #pragma unroll
        for (int i = 0; i < 4; i++)
            #pragma unroll
            for (int j = 0; j < 4; j++)
                acc[i][j] = __builtin_amdgcn_mfma_f32_16x16x32_bf16(af[i], bfr[j], acc[i][j], 0, 0, 0);
        __syncthreads();
    }
    #pragma unroll
    for (int j = 0; j < 4; j++) {
        const int gc = n0 + wc * 64 + j * 16 + lq;
        const float bv = bias[gc];
        #pragma unroll
        for (int i = 0; i < 4; i++) {
            #pragma unroll
            for (int r = 0; r < 4; r++) {
                const int gr = m0 + wr * 64 + i * 16 + quad * 4 + r;
                float v = (acc[i][j][r] + bv) * scale;
                if (RELU) v = fmaxf(v, 0.f);
                if (OUTF) outf[(size_t)gr * N + gc] = v;
                if (OUTB) outb[(size_t)gr * N + gc] = (bf16)v;
            }
        }
    }
}

// W1 relu GEMM: M=4096,N=4096,K=1024; 1-D grid 1024, XCD-swizzled (4 m-tiles/XCD)
__global__ __launch_bounds__(256) void gemm_bf16relu(const bf16* A, const bf16* Bt, const float* bias,
                                                     bf16* out) {
    const int bid = blockIdx.x;
    const int xcd = bid & 7, j = bid >> 3;     // j in [0,128)
    const int mt = xcd * 4 + (j >> 5);
    const int nt = j & 31;
    gemm_core<1, 0, 1>(A, Bt, bias, 1.f, nullptr, out, 4096, 4096, 1024, mt * 128, nt * 128);
}

// fused q,k,v projection; q pre-scaled by 0.125*log2e. 1-D grid 768, z-inner so
// 24 consecutive blocks share one A-tile; 4 m-tiles per XCD.
__global__ __launch_bounds__(256) void gemm_qkv(const bf16* A, const bf16* Wt,
                                                const float* bq, const float* bk, const float* bv,
                                                bf16* out) {
    const int bid = blockIdx.x;
    const int xcd = bid & 7, j = bid >> 3;     // j in [0,96)
    const int mloc = j / 24, r = j % 24;
    const int z = r >> 3, nt = r & 7;
    const int mt = xcd * 4 + mloc;
    const bf16* Bt = Wt + (size_t)z * 1024 * 1024;
    const float* bias = (z == 0) ? bq : (z == 1) ? bk : bv;
    bf16* o = out + (size_t)z * 4096 * 1024;
    const float scale = (z == 0) ? 0.125f * LOG2E : 1.f;
    gemm_core<0, 0, 1>(A, Bt, bias, scale, nullptr, o, 4096, 1024, 1024, mt * 128, nt * 128);
}

// ---------------- 128x64-tile BK=64 GEMM for N=1024 (Wo, W2), split-K=2 ----------------
// 1-D grid 2*(M/128)*(N/64)=1024 (4 blocks/CU), XCD-swizzled within each split half.
// Each half accumulates over K/2 and writes an f32 partial; bias folded into half 0.
// The downstream ln_kernel sums the two partials (+residual) — no extra reduce pass.
__global__ __launch_bounds__(256) void gemm_n1024(const bf16* __restrict__ A, const bf16* __restrict__ Bt,
                                                  const float* __restrict__ bias, float* __restrict__ out,
                                                  int K) {
    __shared__ bf16 As[128 * 64];
    __shared__ bf16 Bs[64 * 64];
    const int bid = blockIdx.x;
    const int xcd = bid & 7, j = bid >> 3;     // j in [0,128)
    const int sk = j >> 6, j2 = j & 63;        // split-K half, tile idx in [0,64)
    const int mt = xcd * 4 + (j2 >> 4);
    const int nt = j2 & 15;
    const int m0 = mt * 128, n0 = nt * 64;
    const int Kh = K >> 1;
    const int tid = threadIdx.x, wave = tid >> 6, lane = tid & 63;
    const int wr = wave >> 1, wc = wave & 1;
    const int quad = lane >> 4, lq = lane & 15;

    floatx4 acc[4][2] = {};
    const bf16* Ap = A + (size_t)m0 * K + (size_t)sk * Kh;
    const bf16* Bp = Bt + (size_t)n0 * K + (size_t)sk * Kh;

    for (int k0 = 0; k0 < Kh; k0 += 64) {
        stage_tile_sw<128, 64>(As, Ap + k0, K, wave, lane);
        stage_tile_sw<64, 64>(Bs, Bp + k0, K, wave, lane);
        __syncthreads();
        #pragma unroll
        for (int kk = 0; kk < 2; kk++) {
            const int chs = ((kk * 4 + quad) ^ (lq & 7)) * 8;
            bf16x8 af[4], bfr[2];
            #pragma unroll
            for (int i = 0; i < 4; i++)
                af[i] = *(const bf16x8*)&As[(wr * 64 + i * 16 + lq) * 64 + chs];
            #pragma unroll
            for (int jj = 0; jj < 2; jj++)
                bfr[jj] = *(const bf16x8*)&Bs[(wc * 32 + jj * 16 + lq) * 64 + chs];
            #pragma unroll
            for (int i = 0; i < 4; i++)
                #pragma unroll
                for (int jj = 0; jj < 2; jj++)
                    acc[i][jj] = __builtin_amdgcn_mfma_f32_16x16x32_bf16(af[i], bfr[jj], acc[i][jj], 0, 0, 0);
        }
        __syncthreads();
    }
    float* op = out + (size_t)sk * 4194304;    // partial-sum buffer for this half
    #pragma unroll
    for (int jj = 0; jj < 2; jj++) {
        const int gc = n0 + wc * 32 + jj * 16 + lq;
        const float bv = sk ? 0.f : bias[gc];
        #pragma unroll
        for (int i = 0; i < 4; i++)
            #pragma unroll
            for (int r = 0; r < 4; r++) {
                const int gr = m0 + wr * 64 + i * 16 + quad * 4 + r;
                op[(size_t)gr * 1024 + gc] = acc[i][jj][r] + bv;
            }
    }
}

// ---------------- fused per-layer weight transpose+convert ----------------
__device__ __forceinline__ void ttile(const float* __restrict__ src, bf16* __restrict__ dst,
                                      int K, int N, int n0, int k0) {
    __shared__ float t[32][33];
    const int tx = threadIdx.x & 31, ty = threadIdx.x >> 5;
    #pragma unroll
    for (int i = 0; i < 4; i++)
        t[ty + i * 8][tx] = src[(size_t)(k0 + ty + i * 8) * N + n0 + tx];
    __syncthreads();
    #pragma unroll
    for (int i = 0; i < 4; i++)
        dst[(size_t)(n0 + ty + i * 8) * K + k0 + tx] = (bf16)t[tx][ty + i * 8];
}

__global__ __launch_bounds__(256) void transpose_all(const float* Wq, const float* Wk, const float* Wv,
                                                     const float* Wo, const float* W1, const float* W2,
                                                     bf16* qkvT, bf16* oT, bf16* w1T, bf16* w2T) {
    const int bx = blockIdx.x;
    if (bx < 4096) {
        const int z = bx >> 10, tile = bx & 1023;
        const float* s = (z == 0) ? Wq : (z == 1) ? Wk : (z == 2) ? Wv : Wo;
        bf16* d = (z == 3) ? oT : qkvT + (size_t)z * 1048576;
        ttile(s, d, 1024, 1024, (tile & 31) * 32, (tile >> 5) * 32);
    } else if (bx < 8192) {
        const int tile = bx - 4096;
        ttile(W1, w1T, 1024, 4096, (tile & 127) * 32, (tile >> 7) * 32);
    } else {
        const int tile = bx - 8192;
        ttile(W2, w2T, 4096, 1024, (tile & 31) * 32, (tile >> 5) * 32);
    }
}

// v [4096, h*64+d] bf16 -> vT [bh][d][L] bf16
__global__ __launch_bounds__(256) void transpose_v(const bf16* v, bf16* vT) {
    __shared__ bf16 t[32][33];
    const int l0 = blockIdx.x * 32, d0 = blockIdx.y * 32, bh = blockIdx.z;
    const int b = bh >> 4, h = bh & 15;
    const int tx = threadIdx.x & 31, ty = threadIdx.x >> 5;
    #pragma unroll
    for (int i = 0; i < 4; i++)
        t[ty + i * 8][tx] = v[(size_t)(b * 1024 + l0 + ty + i * 8) * 1024 + h * 64 + d0 + tx];
    __syncthreads();
    #pragma unroll
    for (int i = 0; i < 4; i++)
        vT[((size_t)bh * 64 + d0 + ty + i * 8) * 1024 + l0 + tx] = t[tx][ty + i * 8];
}

__global__ __launch_bounds__(256) void cvt_f32_bf16(const float* src, bf16* dst) {
    const int i = (blockIdx.x * 256 + threadIdx.x) * 4;
    const float4 v = *(const float4*)(src + i);
    bf16 t4[4] = {(bf16)v.x, (bf16)v.y, (bf16)v.z, (bf16)v.w};
    *(uint64_t*)(dst + i) = *(const uint64_t*)t4;
}

// ---------------- LayerNorm( a0 + a1 + res ) — a0/a1 are the split-K partials ----------------
__global__ __launch_bounds__(256) void ln_kernel(const float* __restrict__ a, const float* __restrict__ a2,
                                                 const float* __restrict__ res,
                                                 const float* __restrict__ gamma, const float* __restrict__ beta,
                                                 float* __restrict__ outf, bf16* __restrict__ outb) {
    const int row = blockIdx.x, tid = threadIdx.x;
    const size_t base = (size_t)row * 1024 + tid * 4;
    const float4 av  = *(const float4*)(a + base);
    const float4 a2v = *(const float4*)(a2 + base);
    const float4 rv  = *(const float4*)(res + base);
    float x0 = av.x + a2v.x + rv.x, x1 = av.y + a2v.y + rv.y;
    float x2 = av.z + a2v.z + rv.z, x3 = av.w + a2v.w + rv.w;
    float s  = x0 + x1 + x2 + x3;
    float sq = x0 * x0 + x1 * x1 + x2 * x2 + x3 * x3;
    #pragma unroll
    for (int off = 32; off; off >>= 1) {
        s  += __shfl_xor(s,  off, 64);
        sq += __shfl_xor(sq, off, 64);
    }
    __shared__ float red[8];
    const int wave = tid >> 6, lane = tid & 63;
    if (lane == 0) { red[wave] = s; red[wave + 4] = sq; }
    __syncthreads();
    const float S  = red[0] + red[1] + red[2] + red[3];
    const float SQ = red[4] + red[5] + red[6] + red[7];
    const float mean = S * (1.f / 1024.f);
    const float var  = SQ * (1.f / 1024.f) - mean * mean;
    const float rstd = rsqrtf(var + 1e-6f);
    const int c = tid * 4;
    const float4 g  = *(const float4*)(gamma + c);
    const float4 be = *(const float4*)(beta + c);
    float y0 = (x0 - mean) * rstd * g.x + be.x;
    float y1 = (x1 - mean) * rstd * g.y + be.y;
    float y2 = (x2 - mean) * rstd * g.z + be.z;
    float y3 = (x3 - mean) * rstd * g.w + be.w;
    float4 yo; yo.x = y0; yo.y = y1; yo.z = y2; yo.w = y3;
    *(float4*)(outf + base) = yo;
    bf16 t4[4] = {(bf16)y0, (bf16)y1, (bf16)y2, (bf16)y3};
    *(uint64_t*)(outb + base) = *(const uint64_t*)t4;
}

// ---------------- flash attention (R2 version, verified) ----------------
__global__ __launch_bounds__(256, 2) void attn_kernel(const bf16* __restrict__ Q, const bf16* __restrict__ Kg,
                                                      const bf16* __restrict__ Vt, bf16* __restrict__ O) {
    __shared__ bf16 Ks[128 * 64];
    __shared__ bf16 Vs[64 * 128];
    __shared__ bf16 Ps[128 * 128];
    const int bh = blockIdx.x, qt = blockIdx.y;
    const int b = bh >> 4, h = bh & 15;
    const int tid = threadIdx.x, wave = tid >> 6, lane = tid & 63;
    const int quad = lane >> 4, lq = lane & 15;

    const bf16* qg = Q + ((size_t)b * 1024 + qt * 128) * 1024 + h * 64;
    const bf16* kg = Kg + (size_t)b * 1024 * 1024 + h * 64;
    const bf16* vg = Vt + (size_t)bh * 64 * 1024;

    stage_tile_sw<128, 64>(Ps, qg, 1024, wave, lane);
    __syncthreads();
    bf16x8 aq[2][2];
    #pragma unroll
    for (int i = 0; i < 2; i++)
        #pragma unroll
        for (int kk = 0; kk < 2; kk++) {
            const int row = wave * 32 + i * 16 + lq;
            const int chs = (kk * 4 + quad) ^ (lq & 7);
            aq[i][kk] = *(const bf16x8*)&Ps[row * 64 + chs * 8];
        }

    floatx4 oacc[2][4] = {};
    float lsum[2][4] = {};

    for (int kt = 0; kt < 1024; kt += 128) {
        stage_tile_sw<128, 64>(Ks, kg + (size_t)kt * 1024, 1024, wave, lane);
        stage_tile_sw<64, 128>(Vs, vg + kt, 1024, wave, lane);
        __syncthreads();

        floatx4 sacc[2][8] = {};
        #pragma unroll
        for (int kk = 0; kk < 2; kk++)
            #pragma unroll
            for (int j = 0; j < 8; j++) {
                const int chs = (kk * 4 + quad) ^ (lq & 7);
                bf16x8 bk = *(const bf16x8*)&Ks[(j * 16 + lq) * 64 + chs * 8];
                sacc[0][j] = __builtin_amdgcn_mfma_f32_16x16x32_bf16(aq[0][kk], bk, sacc[0][j], 0, 0, 0);
                sacc[1][j] = __builtin_amdgcn_mfma_f32_16x16x32_bf16(aq[1][kk], bk, sacc[1][j], 0, 0, 0);
            }

        #pragma unroll
        for (int i = 0; i < 2; i++)
            #pragma unroll
            for (int r = 0; r < 4; r++) {
                const int row = wave * 32 + i * 16 + quad * 4 + r;
                const int rb = row & 7;
                float ls = 0.f;
                #pragma unroll
                for (int j = 0; j < 8; j++) {
                    const float pv = exp2f(sacc[i][j][r]);
                    ls += pv;
                    const int col = j * 16 + lq;
                    Ps[row * 128 + ((col >> 3) ^ rb) * 8 + (col & 7)] = (bf16)pv;
                }
                lsum[i][r] += ls;
            }

        #pragma unroll
        for (int kk = 0; kk < 4; kk++) {
            bf16x8 ap[2];
            #pragma unroll
            for (int i = 0; i < 2; i++) {
                const int row = wave * 32 + i * 16 + lq;
                const int chs = (kk * 4 + quad) ^ (lq & 7);
                ap[i] = *(const bf16x8*)&Ps[row * 128 + chs * 8];
            }
            #pragma unroll
            for (int dj = 0; dj < 4; dj++) {
                const int chs = (kk * 4 + quad) ^ (lq & 7);
                bf16x8 bv = *(const bf16x8*)&Vs[(dj * 16 + lq) * 128 + chs * 8];
                oacc[0][dj] = __builtin_amdgcn_mfma_f32_16x16x32_bf16(ap[0], bv, oacc[0][dj], 0, 0, 0);
                oacc[1][dj] = __builtin_amdgcn_mfma_f32_16x16x32_bf16(ap[1], bv, oacc[1][dj], 0, 0, 0);
            }
        }
        __syncthreads();
    }

    #pragma unroll
    for (int i = 0; i < 2; i++)
        #pragma unroll
        for (int r = 0; r < 4; r++) {
            float l = lsum[i][r];
            l += __shfl_xor(l, 1, 64); l += __shfl_xor(l, 2, 64);
            l += __shfl_xor(l, 4, 64); l += __shfl_xor(l, 8, 64);
            lsum[i][r] = 1.f / l;
        }
    #pragma unroll
    for (int i = 0; i < 2; i++)
        #pragma unroll
        for (int dj = 0; dj < 4; dj++)
            #pragma unroll
            for (int r = 0; r < 4; r++) {
                const int row = qt * 128 + wave * 32 + i * 16 + quad * 4 + r;
                O[((size_t)b * 1024 + row) * 1024 + h * 64 + dj * 16 + lq] = (bf16)(oacc[i][dj][r] * lsum[i][r]);
            }
}

// ---------------- host ----------------
extern "C" void kernel_launch(void* const* d_in, const int* in_sizes, int n_in,
                              void* d_out, int out_size, void* d_ws, size_t ws_size,
                              hipStream_t stream) {
    const float* queries = (const float*)d_in[0];
    const float* Wq = (const float*)d_in[1];  const float* bq = (const float*)d_in[2];
    const float* Wk = (const float*)d_in[3];  const float* bk = (const float*)d_in[4];
    const float* Wv = (const float*)d_in[5];  const float* bv = (const float*)d_in[6];
    const float* Wo = (const float*)d_in[7];  const float* bo = (const float*)d_in[8];
    const float* ln1_s = (const float*)d_in[9];   const float* ln1_b = (const float*)d_in[10];
    const float* ln2_s = (const float*)d_in[11];  const float* ln2_b = (const float*)d_in[12];
    const float* W1 = (const float*)d_in[13]; const float* b1 = (const float*)d_in[14];
    const float* W2 = (const float*)d_in[15]; const float* b2 = (const float*)d_in[16];

    char* p = (char*)d_ws;
    size_t off = 0;
    auto take = [&](size_t bytes) { void* r = p + off; off += bytes; return r; };
    bf16*  WqkvT = (bf16*)take(6291456);
    bf16*  WoT   = (bf16*)take(2097152);
    bf16*  W1T   = (bf16*)take(8388608);
    bf16*  W2T   = (bf16*)take(8388608);
    bf16*  x_bf  = (bf16*)take(8388608);
    float* xf    = (float*)take(16777216);
    bf16*  qkvb  = (bf16*)take(25165824);
    bf16*  vTb   = (bf16*)take(8388608);
    bf16*  updb  = (bf16*)take(8388608);
    float* az    = (float*)take(33554432);   // 2x f32 partials (split-K)
    float* hf    = (float*)take(16777216);
    bf16*  hbf   = (bf16*)take(8388608);
    bf16*  tmlp  = (bf16*)take(33554432);

    cvt_f32_bf16<<<4096, 256, 0, stream>>>(queries, x_bf);

    for (int l = 0; l < 4; ++l) {
        const size_t w1k = (size_t)l * 1024 * 1024;
        const size_t w4m = (size_t)l * 4096 * 1024;
        transpose_all<<<12288, 256, 0, stream>>>(Wq + w1k, Wk + w1k, Wv + w1k, Wo + w1k,
                                                 W1 + w4m, W2 + w4m, WqkvT, WoT, W1T, W2T);

        gemm_qkv<<<768, 256, 0, stream>>>(x_bf, WqkvT,
                                          bq + l * 1024, bk + l * 1024, bv + l * 1024, qkvb);
        transpose_v<<<dim3(32, 2, 64), 256, 0, stream>>>(qkvb + 2 * 4194304, vTb);
        attn_kernel<<<dim3(64, 8), 256, 0, stream>>>(qkvb, qkvb + 4194304, vTb, updb);
        gemm_n1024<<<1024, 256, 0, stream>>>(updb, WoT, bo + l * 1024, az, 1024);
        ln_kernel<<<4096, 256, 0, stream>>>(az, az + 4194304, (l == 0) ? queries : xf,
                                            ln1_s + l * 1024, ln1_b + l * 1024, hf, hbf);
        gemm_bf16relu<<<1024, 256, 0, stream>>>(hbf, W1T, b1 + l * 4096, tmlp);
        gemm_n1024<<<1024, 256, 0, stream>>>(tmlp, W2T, b2 + l * 1024, az, 4096);
        ln_kernel<<<4096, 256, 0, stream>>>(az, az + 4194304, hf, ln2_s + l * 1024, ln2_b + l * 1024,
                                            (l == 3) ? (float*)d_out : xf, x_bf);
    }
}

// Round 2
// 1089.386 us; speedup vs baseline: 1.0613x; 1.0584x over previous
//
#include <hip/hip_runtime.h>
#include <stdint.h>

typedef __bf16 bf16;
typedef __bf16 bf16x8 __attribute__((ext_vector_type(8)));
typedef float floatx4 __attribute__((ext_vector_type(4)));

#define LOG2E 1.44269504088896340736f

// ---------------- async global->LDS (16B/lane, wave-uniform LDS base) ----------------
__device__ __forceinline__ void gl2lds16(const bf16* g, bf16* l) {
    __builtin_amdgcn_global_load_lds((__attribute__((address_space(1))) void*)g,
                                     (__attribute__((address_space(3))) void*)l,
                                     16, 0, 0);
}

// chunk swizzle (16B chunks): spreads row-strided b128 reads across all 32 banks
template<int COLS>
__device__ __forceinline__ int swz(int ch, int r) {
    if constexpr (COLS == 32) return ch ^ ((r >> 1) & 3);
    else                      return ch ^ (r & 7);
}

// Stage ROWS x COLS bf16 tile into LDS, lane-contiguous dest, source chunk-swizzled.
template<int ROWS, int COLS>
__device__ __forceinline__ void stage_tile_sw(bf16* lds, const bf16* g, int srcStride, int wave, int lane) {
    constexpr int NINST = (ROWS * COLS * 2) / 1024;
    constexpr int ROWB  = COLS * 2;
    #pragma unroll
    for (int u = 0; u < NINST / 4; ++u) {
        int t  = wave + u * 4;
        int ob = t * 1024 + lane * 16;
        int r  = ob / ROWB;
        int ch = (ob % ROWB) >> 4;
        int sc = swz<COLS>(ch, r);
        gl2lds16(g + r * srcStride + sc * 8, lds + t * 512);
    }
}

// ---------------- 128x128 bf16 GEMM core: C[M,N] = A[M,K] * Bt[N,K]^T ----------------
template<int RELU, int OUTF, int OUTB>
__device__ __forceinline__ void gemm_core(const bf16* __restrict__ A, const bf16* __restrict__ Bt,
                                          const float* __restrict__ bias, float scale,
                                          float* __restrict__ outf, bf16* __restrict__ outb,
                                          int M, int N, int K, int m0, int n0) {
    __shared__ bf16 As[128 * 32];
    __shared__ bf16 Bs[128 * 32];
    const int tid = threadIdx.x, wave = tid >> 6, lane = tid & 63;
    const int wr = wave >> 1, wc = wave & 1;
    const int quad = lane >> 4, lq = lane & 15;
    const int swa = quad ^ ((lq >> 1) & 3);

    floatx4 acc[4][4] = {};
    const bf16* Ap = A + (size_t)m0 * K;
    const bf16* Bp = Bt + (size_t)n0 * K;

    for (int k0 = 0; k0 < K; k0 += 32) {
        stage_tile_sw<128, 32>(As, Ap + k0, K, wave, lane);
        stage_tile_sw<128, 32>(Bs, Bp + k0, K, wave, lane);
        __syncthreads();
        bf16x8 af[4], bfr[4];
        #pragma unroll
        for (int i = 0; i < 4; i++)
            af[i] = *(const bf16x8*)&As[(wr * 64 + i * 16 + lq) * 32 + swa * 8];
        #pragma unroll
        for (int j = 0; j < 4; j++)
            bfr[j] = *(const bf16x8*)&Bs[(wc * 64 + j * 16 + lq) * 32 + swa * 8];
        #pragma unroll
        for (int i = 0; i < 4; i++)
            #pragma unroll
            for (int j = 0; j < 4; j++)
                acc[i][j] = __builtin_amdgcn_mfma_f32_16x16x32_bf16(af[i], bfr[j], acc[i][j], 0, 0, 0);
        __syncthreads();
    }
    #pragma unroll
    for (int j = 0; j < 4; j++) {
        const int gc = n0 + wc * 64 + j * 16 + lq;
        const float bv = bias[gc];
        #pragma unroll
        for (int i = 0; i < 4; i++) {
            #pragma unroll
            for (int r = 0; r < 4; r++) {
                const int gr = m0 + wr * 64 + i * 16 + quad * 4 + r;
                float v = (acc[i][j][r] + bv) * scale;
                if (RELU) v = fmaxf(v, 0.f);
                if (OUTF) outf[(size_t)gr * N + gc] = v;
                if (OUTB) outb[(size_t)gr * N + gc] = (bf16)v;
            }
        }
    }
}

// W1 relu GEMM: M=4096,N=4096,K=1024; 1-D grid 1024, XCD-swizzled (4 m-tiles/XCD)
__global__ __launch_bounds__(256) void gemm_bf16relu(const bf16* A, const bf16* Bt, const float* bias,
                                                     bf16* out) {
    const int bid = blockIdx.x;
    const int xcd = bid & 7, j = bid >> 3;     // j in [0,128)
    const int mt = xcd * 4 + (j >> 5);
    const int nt = j & 31;
    gemm_core<1, 0, 1>(A, Bt, bias, 1.f, nullptr, out, 4096, 4096, 1024, mt * 128, nt * 128);
}

// fused q,k,v projection; q pre-scaled by 0.125*log2e. 1-D grid 768, z-inner so
// 24 consecutive blocks share one A-tile; 4 m-tiles per XCD.
__global__ __launch_bounds__(256) void gemm_qkv(const bf16* A, const bf16* Wt,
                                                const float* bq, const float* bk, const float* bv,
                                                bf16* out) {
    const int bid = blockIdx.x;
    const int xcd = bid & 7, j = bid >> 3;     // j in [0,96)
    const int mloc = j / 24, r = j % 24;
    const int z = r >> 3, nt = r & 7;
    const int mt = xcd * 4 + mloc;
    const bf16* Bt = Wt + (size_t)z * 1024 * 1024;
    const float* bias = (z == 0) ? bq : (z == 1) ? bk : bv;
    bf16* o = out + (size_t)z * 4096 * 1024;
    const float scale = (z == 0) ? 0.125f * LOG2E : 1.f;
    gemm_core<0, 0, 1>(A, Bt, bias, scale, nullptr, o, 4096, 1024, 1024, mt * 128, nt * 128);
}

// ---------------- 128x64-tile BK=64 GEMM for N=1024 (Wo, W2), split-K=2 ----------------
__global__ __launch_bounds__(256) void gemm_n1024(const bf16* __restrict__ A, const bf16* __restrict__ Bt,
                                                  const float* __restrict__ bias, float* __restrict__ out,
                                                  int K) {
    __shared__ bf16 As[128 * 64];
    __shared__ bf16 Bs[64 * 64];
    const int bid = blockIdx.x;
    const int xcd = bid & 7, j = bid >> 3;     // j in [0,128)
    const int sk = j >> 6, j2 = j & 63;        // split-K half, tile idx in [0,64)
    const int mt = xcd * 4 + (j2 >> 4);
    const int nt = j2 & 15;
    const int m0 = mt * 128, n0 = nt * 64;
    const int Kh = K >> 1;
    const int tid = threadIdx.x, wave = tid >> 6, lane = tid & 63;
    const int wr = wave >> 1, wc = wave & 1;
    const int quad = lane >> 4, lq = lane & 15;

    floatx4 acc[4][2] = {};
    const bf16* Ap = A + (size_t)m0 * K + (size_t)sk * Kh;
    const bf16* Bp = Bt + (size_t)n0 * K + (size_t)sk * Kh;

    for (int k0 = 0; k0 < Kh; k0 += 64) {
        stage_tile_sw<128, 64>(As, Ap + k0, K, wave, lane);
        stage_tile_sw<64, 64>(Bs, Bp + k0, K, wave, lane);
        __syncthreads();
        #pragma unroll
        for (int kk = 0; kk < 2; kk++) {
            const int chs = ((kk * 4 + quad) ^ (lq & 7)) * 8;
            bf16x8 af[4], bfr[2];
            #pragma unroll
            for (int i = 0; i < 4; i++)
                af[i] = *(const bf16x8*)&As[(wr * 64 + i * 16 + lq) * 64 + chs];
            #pragma unroll
            for (int jj = 0; jj < 2; jj++)
                bfr[jj] = *(const bf16x8*)&Bs[(wc * 32 + jj * 16 + lq) * 64 + chs];
            #pragma unroll
            for (int i = 0; i < 4; i++)
                #pragma unroll
                for (int jj = 0; jj < 2; jj++)
                    acc[i][jj] = __builtin_amdgcn_mfma_f32_16x16x32_bf16(af[i], bfr[jj], acc[i][jj], 0, 0, 0);
        }
        __syncthreads();
    }
    float* op = out + (size_t)sk * 4194304;    // partial-sum buffer for this half
    #pragma unroll
    for (int jj = 0; jj < 2; jj++) {
        const int gc = n0 + wc * 32 + jj * 16 + lq;
        const float bv = sk ? 0.f : bias[gc];
        #pragma unroll
        for (int i = 0; i < 4; i++)
            #pragma unroll
            for (int r = 0; r < 4; r++) {
                const int gr = m0 + wr * 64 + i * 16 + quad * 4 + r;
                op[(size_t)gr * 1024 + gc] = acc[i][jj][r] + bv;
            }
    }
}

// ---------------- fused per-layer weight transpose+convert ----------------
__device__ __forceinline__ void ttile(const float* __restrict__ src, bf16* __restrict__ dst,
                                      int K, int N, int n0, int k0) {
    __shared__ float t[32][33];
    const int tx = threadIdx.x & 31, ty = threadIdx.x >> 5;
    #pragma unroll
    for (int i = 0; i < 4; i++)
        t[ty + i * 8][tx] = src[(size_t)(k0 + ty + i * 8) * N + n0 + tx];
    __syncthreads();
    #pragma unroll
    for (int i = 0; i < 4; i++)
        dst[(size_t)(n0 + ty + i * 8) * K + k0 + tx] = (bf16)t[tx][ty + i * 8];
}

__global__ __launch_bounds__(256) void transpose_all(const float* Wq, const float* Wk, const float* Wv,
                                                     const float* Wo, const float* W1, const float* W2,
                                                     bf16* qkvT, bf16* oT, bf16* w1T, bf16* w2T) {
    const int bx = blockIdx.x;
    if (bx < 4096) {
        const int z = bx >> 10, tile = bx & 1023;
        const float* s = (z == 0) ? Wq : (z == 1) ? Wk : (z == 2) ? Wv : Wo;
        bf16* d = (z == 3) ? oT : qkvT + (size_t)z * 1048576;
        ttile(s, d, 1024, 1024, (tile & 31) * 32, (tile >> 5) * 32);
    } else if (bx < 8192) {
        const int tile = bx - 4096;
        ttile(W1, w1T, 1024, 4096, (tile & 127) * 32, (tile >> 7) * 32);
    } else {
        const int tile = bx - 8192;
        ttile(W2, w2T, 4096, 1024, (tile & 31) * 32, (tile >> 5) * 32);
    }
}

// v [4096, h*64+d] bf16 -> vT [bh][d][L] with per-128-L-block k-permutation:
// within each 128 block, element position l'*8+j holds the value at L = 16*j + l'.
// This makes vT chunk c carry the k-set {16j + c}, matching the attn P-store layout,
// so PV MFMA operands pair identical logical k per hw slot.
__global__ __launch_bounds__(256) void transpose_v(const bf16* v, bf16* vT) {
    __shared__ float t[128][34];
    const int l0 = blockIdx.x * 128, d0 = blockIdx.y * 32, bh = blockIdx.z;
    const int b = bh >> 4, h = bh & 15;
    const int tid = threadIdx.x;
    // load 128 L x 32 d (bf16) as 2-wide dwords: 16 lanes cover one 32-d row segment
    const int dp = (tid & 15) * 2, lr = tid >> 4;   // lr in [0,16)
    #pragma unroll
    for (int i = 0; i < 8; i++) {
        const int lrow = lr + i * 16;
        bf16 two[2];
        *(uint32_t*)two = *(const uint32_t*)&v[(size_t)(b * 1024 + l0 + lrow) * 1024 + h * 64 + d0 + dp];
        t[lrow][dp]     = (float)two[0];
        t[lrow][dp + 1] = (float)two[1];
    }
    __syncthreads();
    // write: each thread emits two 16B chunks; chunk c = (d<<4)|l' gathers j=0..7
    #pragma unroll
    for (int u2 = 0; u2 < 2; u2++) {
        const int c = tid + u2 * 256;
        const int d = c >> 4, lp = c & 15;
        bf16 pb[8];
        #pragma unroll
        for (int j = 0; j < 8; j++)
            pb[j] = (bf16)t[j * 16 + lp][d];
        *(bf16x8*)&vT[((size_t)bh * 64 + d0 + d) * 1024 + l0 + lp * 8] = *(bf16x8*)pb;
    }
}

__global__ __launch_bounds__(256) void cvt_f32_bf16(const float* src, bf16* dst) {
    const int i = (blockIdx.x * 256 + threadIdx.x) * 4;
    const float4 v = *(const float4*)(src + i);
    bf16 t4[4] = {(bf16)v.x, (bf16)v.y, (bf16)v.z, (bf16)v.w};
    *(uint64_t*)(dst + i) = *(const uint64_t*)t4;
}

// ---------------- LayerNorm( a0 + a1 + res ) — a0/a1 are the split-K partials ----------------
__global__ __launch_bounds__(256) void ln_kernel(const float* __restrict__ a, const float* __restrict__ a2,
                                                 const float* __restrict__ res,
                                                 const float* __restrict__ gamma, const float* __restrict__ beta,
                                                 float* __restrict__ outf, bf16* __restrict__ outb) {
    const int row = blockIdx.x, tid = threadIdx.x;
    const size_t base = (size_t)row * 1024 + tid * 4;
    const float4 av  = *(const float4*)(a + base);
    const float4 a2v = *(const float4*)(a2 + base);
    const float4 rv  = *(const float4*)(res + base);
    float x0 = av.x + a2v.x + rv.x, x1 = av.y + a2v.y + rv.y;
    float x2 = av.z + a2v.z + rv.z, x3 = av.w + a2v.w + rv.w;
    float s  = x0 + x1 + x2 + x3;
    float sq = x0 * x0 + x1 * x1 + x2 * x2 + x3 * x3;
    #pragma unroll
    for (int off = 32; off; off >>= 1) {
        s  += __shfl_xor(s,  off, 64);
        sq += __shfl_xor(sq, off, 64);
    }
    __shared__ float red[8];
    const int wave = tid >> 6, lane = tid & 63;
    if (lane == 0) { red[wave] = s; red[wave + 4] = sq; }
    __syncthreads();
    const float S  = red[0] + red[1] + red[2] + red[3];
    const float SQ = red[4] + red[5] + red[6] + red[7];
    const float mean = S * (1.f / 1024.f);
    const float var  = SQ * (1.f / 1024.f) - mean * mean;
    const float rstd = rsqrtf(var + 1e-6f);
    const int c = tid * 4;
    const float4 g  = *(const float4*)(gamma + c);
    const float4 be = *(const float4*)(beta + c);
    float y0 = (x0 - mean) * rstd * g.x + be.x;
    float y1 = (x1 - mean) * rstd * g.y + be.y;
    float y2 = (x2 - mean) * rstd * g.z + be.z;
    float y3 = (x3 - mean) * rstd * g.w + be.w;
    float4 yo; yo.x = y0; yo.y = y1; yo.z = y2; yo.w = y3;
    *(float4*)(outf + base) = yo;
    bf16 t4[4] = {(bf16)y0, (bf16)y1, (bf16)y2, (bf16)y3};
    *(uint64_t*)(outb + base) = *(const uint64_t*)t4;
}

// ---------------- flash attention ----------------
// P-store layout change vs R2: Ps logical chunk c of row rho holds k-set {16j + c},
// stored at chunk position c ^ (rho & 7). After QK^T, lane (quad,lq) holds exactly
// chunk c=lq of its 8 rows -> one ds_write_b128 per (i,r) instead of 64 ds_write_b16.
// PV read code is UNCHANGED (same chunk-index formula); V was permuted in transpose_v
// so its chunks carry the same stride-16 k-sets in the same within-chunk order.
__global__ __launch_bounds__(256, 2) void attn_kernel(const bf16* __restrict__ Q, const bf16* __restrict__ Kg,
                                                      const bf16* __restrict__ Vt, bf16* __restrict__ O) {
    __shared__ bf16 Ks[128 * 64];
    __shared__ bf16 Vs[64 * 128];
    __shared__ bf16 Ps[128 * 128];
    const int bh = blockIdx.x, qt = blockIdx.y;
    const int b = bh >> 4, h = bh & 15;
    const int tid = threadIdx.x, wave = tid >> 6, lane = tid & 63;
    const int quad = lane >> 4, lq = lane & 15;

    const bf16* qg = Q + ((size_t)b * 1024 + qt * 128) * 1024 + h * 64;
    const bf16* kg = Kg + (size_t)b * 1024 * 1024 + h * 64;
    const bf16* vg = Vt + (size_t)bh * 64 * 1024;

    stage_tile_sw<128, 64>(Ps, qg, 1024, wave, lane);
    __syncthreads();
    bf16x8 aq[2][2];
    #pragma unroll
    for (int i = 0; i < 2; i++)
        #pragma unroll
        for (int kk = 0; kk < 2; kk++) {
            const int row = wave * 32 + i * 16 + lq;
            const int chs = (kk * 4 + quad) ^ (lq & 7);
            aq[i][kk] = *(const bf16x8*)&Ps[row * 64 + chs * 8];
        }

    floatx4 oacc[2][4] = {};
    float lsum[2][4] = {};

    for (int kt = 0; kt < 1024; kt += 128) {
        stage_tile_sw<128, 64>(Ks, kg + (size_t)kt * 1024, 1024, wave, lane);
        stage_tile_sw<64, 128>(Vs, vg + kt, 1024, wave, lane);
        __syncthreads();

        floatx4 sacc[2][8] = {};
        #pragma unroll
        for (int kk = 0; kk < 2; kk++)
            #pragma unroll
            for (int j = 0; j < 8; j++) {
                const int chs = (kk * 4 + quad) ^ (lq & 7);
                bf16x8 bk = *(const bf16x8*)&Ks[(j * 16 + lq) * 64 + chs * 8];
                sacc[0][j] = __builtin_amdgcn_mfma_f32_16x16x32_bf16(aq[0][kk], bk, sacc[0][j], 0, 0, 0);
                sacc[1][j] = __builtin_amdgcn_mfma_f32_16x16x32_bf16(aq[1][kk], bk, sacc[1][j], 0, 0, 0);
            }

        // softmax-exp + packed P store: one b128 per (i,r)
        #pragma unroll
        for (int i = 0; i < 2; i++)
            #pragma unroll
            for (int r = 0; r < 4; r++) {
                const int row = wave * 32 + i * 16 + quad * 4 + r;
                float ls = 0.f;
                bf16 pb[8];
                #pragma unroll
                for (int j = 0; j < 8; j++) {
                    const float pv = exp2f(sacc[i][j][r]);
                    ls += pv;
                    pb[j] = (bf16)pv;
                }
                lsum[i][r] += ls;
                *(bf16x8*)&Ps[row * 128 + (lq ^ (row & 7)) * 8] = *(const bf16x8*)pb;
            }

        #pragma unroll
        for (int kk = 0; kk < 4; kk++) {
            bf16x8 ap[2];
            #pragma unroll
            for (int i = 0; i < 2; i++) {
                const int row = wave * 32 + i * 16 + lq;
                const int chs = (kk * 4 + quad) ^ (lq & 7);
                ap[i] = *(const bf16x8*)&Ps[row * 128 + chs * 8];
            }
            #pragma unroll
            for (int dj = 0; dj < 4; dj++) {
                const int chs = (kk * 4 + quad) ^ (lq & 7);
                bf16x8 bv = *(const bf16x8*)&Vs[(dj * 16 + lq) * 128 + chs * 8];
                oacc[0][dj] = __builtin_amdgcn_mfma_f32_16x16x32_bf16(ap[0], bv, oacc[0][dj], 0, 0, 0);
                oacc[1][dj] = __builtin_amdgcn_mfma_f32_16x16x32_bf16(ap[1], bv, oacc[1][dj], 0, 0, 0);
            }
        }
        __syncthreads();
    }

    #pragma unroll
    for (int i = 0; i < 2; i++)
        #pragma unroll
        for (int r = 0; r < 4; r++) {
            float l = lsum[i][r];
            l += __shfl_xor(l, 1, 64); l += __shfl_xor(l, 2, 64);
            l += __shfl_xor(l, 4, 64); l += __shfl_xor(l, 8, 64);
            lsum[i][r] = 1.f / l;
        }
    #pragma unroll
    for (int i = 0; i < 2; i++)
        #pragma unroll
        for (int dj = 0; dj < 4; dj++)
            #pragma unroll
            for (int r = 0; r < 4; r++) {
                const int row = qt * 128 + wave * 32 + i * 16 + quad * 4 + r;
                O[((size_t)b * 1024 + row) * 1024 + h * 64 + dj * 16 + lq] = (bf16)(oacc[i][dj][r] * lsum[i][r]);
            }
}

// ---------------- host ----------------
extern "C" void kernel_launch(void* const* d_in, const int* in_sizes, int n_in,
                              void* d_out, int out_size, void* d_ws, size_t ws_size,
                              hipStream_t stream) {
    const float* queries = (const float*)d_in[0];
    const float* Wq = (const float*)d_in[1];  const float* bq = (const float*)d_in[2];
    const float* Wk = (const float*)d_in[3];  const float* bk = (const float*)d_in[4];
    const float* Wv = (const float*)d_in[5];  const float* bv = (const float*)d_in[6];
    const float* Wo = (const float*)d_in[7];  const float* bo = (const float*)d_in[8];
    const float* ln1_s = (const float*)d_in[9];   const float* ln1_b = (const float*)d_in[10];
    const float* ln2_s = (const float*)d_in[11];  const float* ln2_b = (const float*)d_in[12];
    const float* W1 = (const float*)d_in[13]; const float* b1 = (const float*)d_in[14];
    const float* W2 = (const float*)d_in[15]; const float* b2 = (const float*)d_in[16];

    char* p = (char*)d_ws;
    size_t off = 0;
    auto take = [&](size_t bytes) { void* r = p + off; off += bytes; return r; };
    bf16*  WqkvT = (bf16*)take(6291456);
    bf16*  WoT   = (bf16*)take(2097152);
    bf16*  W1T   = (bf16*)take(8388608);
    bf16*  W2T   = (bf16*)take(8388608);
    bf16*  x_bf  = (bf16*)take(8388608);
    float* xf    = (float*)take(16777216);
    bf16*  qkvb  = (bf16*)take(25165824);
    bf16*  vTb   = (bf16*)take(8388608);
    bf16*  updb  = (bf16*)take(8388608);
    float* az    = (float*)take(33554432);   // 2x f32 partials (split-K)
    float* hf    = (float*)take(16777216);
    bf16*  hbf   = (bf16*)take(8388608);
    bf16*  tmlp  = (bf16*)take(33554432);

    cvt_f32_bf16<<<4096, 256, 0, stream>>>(queries, x_bf);

    for (int l = 0; l < 4; ++l) {
        const size_t w1k = (size_t)l * 1024 * 1024;
        const size_t w4m = (size_t)l * 4096 * 1024;
        transpose_all<<<12288, 256, 0, stream>>>(Wq + w1k, Wk + w1k, Wv + w1k, Wo + w1k,
                                                 W1 + w4m, W2 + w4m, WqkvT, WoT, W1T, W2T);

        gemm_qkv<<<768, 256, 0, stream>>>(x_bf, WqkvT,
                                          bq + l * 1024, bk + l * 1024, bv + l * 1024, qkvb);
        transpose_v<<<dim3(8, 2, 64), 256, 0, stream>>>(qkvb + 2 * 4194304, vTb);
        attn_kernel<<<dim3(64, 8), 256, 0, stream>>>(qkvb, qkvb + 4194304, vTb, updb);
        gemm_n1024<<<1024, 256, 0, stream>>>(updb, WoT, bo + l * 1024, az, 1024);
        ln_kernel<<<4096, 256, 0, stream>>>(az, az + 4194304, (l == 0) ? queries : xf,
                                            ln1_s + l * 1024, ln1_b + l * 1024, hf, hbf);
        gemm_bf16relu<<<1024, 256, 0, stream>>>(hbf, W1T, b1 + l * 4096, tmlp);
        gemm_n1024<<<1024, 256, 0, stream>>>(tmlp, W2T, b2 + l * 1024, az, 4096);
        ln_kernel<<<4096, 256, 0, stream>>>(az, az + 4194304, hf, ln2_s + l * 1024, ln2_b + l * 1024,
                                            (l == 3) ? (float*)d_out : xf, x_bf);
    }
}

// Round 3
// 1033.955 us; speedup vs baseline: 1.1181x; 1.0536x over previous
//
#include <hip/hip_runtime.h>
#include <stdint.h>

typedef __bf16 bf16;
typedef __bf16 bf16x8 __attribute__((ext_vector_type(8)));
typedef float floatx4 __attribute__((ext_vector_type(4)));

#define LOG2E 1.44269504088896340736f

// ---------------- async global->LDS (16B/lane, wave-uniform LDS base) ----------------
__device__ __forceinline__ void gl2lds16(const bf16* g, bf16* l) {
    __builtin_amdgcn_global_load_lds((__attribute__((address_space(1))) void*)g,
                                     (__attribute__((address_space(3))) void*)l,
                                     16, 0, 0);
}

// chunk swizzle (16B chunks): spreads row-strided b128 reads across all 32 banks
template<int COLS>
__device__ __forceinline__ int swz(int ch, int r) {
    if constexpr (COLS == 32) return ch ^ ((r >> 1) & 3);
    else                      return ch ^ (r & 7);
}

// Stage ROWS x COLS bf16 tile into LDS, lane-contiguous dest, source chunk-swizzled.
template<int ROWS, int COLS>
__device__ __forceinline__ void stage_tile_sw(bf16* lds, const bf16* g, int srcStride, int wave, int lane) {
    constexpr int NINST = (ROWS * COLS * 2) / 1024;
    constexpr int ROWB  = COLS * 2;
    #pragma unroll
    for (int u = 0; u < NINST / 4; ++u) {
        int t  = wave + u * 4;
        int ob = t * 1024 + lane * 16;
        int r  = ob / ROWB;
        int ch = (ob % ROWB) >> 4;
        int sc = swz<COLS>(ch, r);
        gl2lds16(g + r * srcStride + sc * 8, lds + t * 512);
    }
}

// 512-thread version: stage one 128x64 bf16 half-tile (16 KB), rows of 128 B
__device__ __forceinline__ void stage_half_512(bf16* lds, const bf16* g, int srcStride, int wave, int lane) {
    #pragma unroll
    for (int u = 0; u < 2; ++u) {
        int t  = wave + u * 8;          // [0,16) 1KB slots
        int ob = t * 1024 + lane * 16;
        int r  = ob >> 7;
        int ch = (ob >> 4) & 7;
        int sc = ch ^ (r & 7);
        gl2lds16(g + r * srcStride + sc * 8, lds + t * 512);
    }
}

// ---------------- 128x128 bf16 GEMM core: C[M,N] = A[M,K] * Bt[N,K]^T ----------------
template<int RELU, int OUTF, int OUTB>
__device__ __forceinline__ void gemm_core(const bf16* __restrict__ A, const bf16* __restrict__ Bt,
                                          const float* __restrict__ bias, float scale,
                                          float* __restrict__ outf, bf16* __restrict__ outb,
                                          int M, int N, int K, int m0, int n0) {
    __shared__ bf16 As[128 * 32];
    __shared__ bf16 Bs[128 * 32];
    const int tid = threadIdx.x, wave = tid >> 6, lane = tid & 63;
    const int wr = wave >> 1, wc = wave & 1;
    const int quad = lane >> 4, lq = lane & 15;
    const int swa = quad ^ ((lq >> 1) & 3);

    floatx4 acc[4][4] = {};
    const bf16* Ap = A + (size_t)m0 * K;
    const bf16* Bp = Bt + (size_t)n0 * K;

    for (int k0 = 0; k0 < K; k0 += 32) {
        stage_tile_sw<128, 32>(As, Ap + k0, K, wave, lane);
        stage_tile_sw<128, 32>(Bs, Bp + k0, K, wave, lane);
        __syncthreads();
        bf16x8 af[4], bfr[4];
        #pragma unroll
        for (int i = 0; i < 4; i++)
            af[i] = *(const bf16x8*)&As[(wr * 64 + i * 16 + lq) * 32 + swa * 8];
        #pragma unroll
        for (int j = 0; j < 4; j++)
            bfr[j] = *(const bf16x8*)&Bs[(wc * 64 + j * 16 + lq) * 32 + swa * 8];
        #pragma unroll
        for (int i = 0; i < 4; i++)
            #pragma unroll
            for (int j = 0; j < 4; j++)
                acc[i][j] = __builtin_amdgcn_mfma_f32_16x16x32_bf16(af[i], bfr[j], acc[i][j], 0, 0, 0);
        __syncthreads();
    }
    #pragma unroll
    for (int j = 0; j < 4; j++) {
        const int gc = n0 + wc * 64 + j * 16 + lq;
        const float bv = bias[gc];
        #pragma unroll
        for (int i = 0; i < 4; i++) {
            #pragma unroll
            for (int r = 0; r < 4; r++) {
                const int gr = m0 + wr * 64 + i * 16 + quad * 4 + r;
                float v = (acc[i][j][r] + bv) * scale;
                if (RELU) v = fmaxf(v, 0.f);
                if (OUTF) outf[(size_t)gr * N + gc] = v;
                if (OUTB) outb[(size_t)gr * N + gc] = (bf16)v;
            }
        }
    }
}

// ---------------- W1 relu GEMM: 256x256 tile, BK=64, 8 waves, dbuf + 4-phase ----------------
// C[4096,4096] = relu(A[4096,1024] x Bt[4096,1024]^T + bias), bf16 out.
// One __syncthreads (vmcnt+lgkm drain) per K-tile; stages of tile t+1 are issued
// interleaved with the 4 setprio-wrapped MFMA phases of tile t (T3/T5 structure).
__global__ __launch_bounds__(512, 2) void gemm_mlp1(const bf16* __restrict__ A, const bf16* __restrict__ Bt,
                                                    const float* __restrict__ bias, bf16* __restrict__ out) {
    __shared__ bf16 As[2][2][128 * 64];   // [buf][half]
    __shared__ bf16 Bs[2][2][128 * 64];
    const int bid = blockIdx.x;
    const int xcd = bid & 7, j = bid >> 3;          // j in [0,32)
    const int mt = xcd * 2 + (j >> 4), nt = j & 15;
    const int m0 = mt * 256, n0 = nt * 256;
    const int tid = threadIdx.x, wave = tid >> 6, lane = tid & 63;
    const int wr = wave >> 2;           // A-half (rows wr*128..)
    const int wcn = wave & 3;
    const int bwh = wcn >> 1, bwl = wcn & 1;   // B-half, 64-col block within half
    const int quad = lane >> 4, lq = lane & 15;
    constexpr int K = 1024;

    const bf16* Ab0 = A + (size_t)m0 * K;
    const bf16* Ab1 = A + (size_t)(m0 + 128) * K;
    const bf16* Bb0 = Bt + (size_t)n0 * K;
    const bf16* Bb1 = Bt + (size_t)(n0 + 128) * K;

    floatx4 acc[8][4] = {};

    // prologue: stage K-tile 0 into buf 0
    stage_half_512(As[0][0], Ab0, K, wave, lane);
    stage_half_512(As[0][1], Ab1, K, wave, lane);
    stage_half_512(Bs[0][0], Bb0, K, wave, lane);
    stage_half_512(Bs[0][1], Bb1, K, wave, lane);

    for (int kt = 0; kt < 16; ++kt) {
        const int cur = kt & 1, nxt = cur ^ 1;
        const int k1 = (kt + 1) * 64;
        const bool pf = (kt < 15);
        __syncthreads();                 // drains vmcnt(0): tile kt landed; prev reads of buf[nxt] done
        const bf16* Ar = As[cur][wr];
        const bf16* Br = Bs[cur][bwh];
        #pragma unroll
        for (int mh = 0; mh < 2; mh++) {
            bf16x8 af[4][2];
            if (mh == 0 && pf) stage_half_512(As[nxt][0], Ab0 + k1, K, wave, lane);
            #pragma unroll
            for (int i2 = 0; i2 < 4; i2++)
                #pragma unroll
                for (int kk = 0; kk < 2; kk++)
                    af[i2][kk] = *(const bf16x8*)&Ar[(mh * 64 + i2 * 16 + lq) * 64 +
                                                     (((kk * 4 + quad) ^ (lq & 7)) * 8)];
            if (pf) {
                if (mh == 0) stage_half_512(As[nxt][1], Ab1 + k1, K, wave, lane);
                else         stage_half_512(Bs[nxt][1], Bb1 + k1, K, wave, lane);
            }
            #pragma unroll
            for (int nh = 0; nh < 2; nh++) {
                bf16x8 bfr[2][2];
                #pragma unroll
                for (int j2 = 0; j2 < 2; j2++)
                    #pragma unroll
                    for (int kk = 0; kk < 2; kk++)
                        bfr[j2][kk] = *(const bf16x8*)&Br[(bwl * 64 + nh * 32 + j2 * 16 + lq) * 64 +
                                                          (((kk * 4 + quad) ^ (lq & 7)) * 8)];
                if (mh == 0 && nh == 1 && pf) stage_half_512(Bs[nxt][0], Bb0 + k1, K, wave, lane);
                __builtin_amdgcn_s_setprio(1);
                #pragma unroll
                for (int i2 = 0; i2 < 4; i2++)
                    #pragma unroll
                    for (int j2 = 0; j2 < 2; j2++)
                        #pragma unroll
                        for (int kk = 0; kk < 2; kk++)
                            acc[mh * 4 + i2][nh * 2 + j2] =
                                __builtin_amdgcn_mfma_f32_16x16x32_bf16(af[i2][kk], bfr[j2][kk],
                                                                        acc[mh * 4 + i2][nh * 2 + j2], 0, 0, 0);
                __builtin_amdgcn_s_setprio(0);
            }
        }
    }

    #pragma unroll
    for (int j2 = 0; j2 < 4; j2++) {
        const int gc = n0 + bwh * 128 + bwl * 64 + j2 * 16 + lq;
        const float bv = bias[gc];
        #pragma unroll
        for (int i2 = 0; i2 < 8; i2++)
            #pragma unroll
            for (int r = 0; r < 4; r++) {
                const int gr = m0 + wr * 128 + i2 * 16 + quad * 4 + r;
                float v = acc[i2][j2][r] + bv;
                out[(size_t)gr * 4096 + gc] = (bf16)fmaxf(v, 0.f);
            }
    }
}

// fused q,k,v projection; q pre-scaled by 0.125*log2e. 1-D grid 768, z-inner so
// 24 consecutive blocks share one A-tile; 4 m-tiles per XCD.
__global__ __launch_bounds__(256) void gemm_qkv(const bf16* A, const bf16* Wt,
                                                const float* bq, const float* bk, const float* bv,
                                                bf16* out) {
    const int bid = blockIdx.x;
    const int xcd = bid & 7, j = bid >> 3;     // j in [0,96)
    const int mloc = j / 24, r = j % 24;
    const int z = r >> 3, nt = r & 7;
    const int mt = xcd * 4 + mloc;
    const bf16* Bt = Wt + (size_t)z * 1024 * 1024;
    const float* bias = (z == 0) ? bq : (z == 1) ? bk : bv;
    bf16* o = out + (size_t)z * 4096 * 1024;
    const float scale = (z == 0) ? 0.125f * LOG2E : 1.f;
    gemm_core<0, 0, 1>(A, Bt, bias, scale, nullptr, o, 4096, 1024, 1024, mt * 128, nt * 128);
}

// ---------------- 128x64-tile BK=64 GEMM for N=1024 (Wo, W2), split-K=2 ----------------
__global__ __launch_bounds__(256) void gemm_n1024(const bf16* __restrict__ A, const bf16* __restrict__ Bt,
                                                  const float* __restrict__ bias, float* __restrict__ out,
                                                  int K) {
    __shared__ bf16 As[128 * 64];
    __shared__ bf16 Bs[64 * 64];
    const int bid = blockIdx.x;
    const int xcd = bid & 7, j = bid >> 3;     // j in [0,128)
    const int sk = j >> 6, j2 = j & 63;        // split-K half, tile idx in [0,64)
    const int mt = xcd * 4 + (j2 >> 4);
    const int nt = j2 & 15;
    const int m0 = mt * 128, n0 = nt * 64;
    const int Kh = K >> 1;
    const int tid = threadIdx.x, wave = tid >> 6, lane = tid & 63;
    const int wr = wave >> 1, wc = wave & 1;
    const int quad = lane >> 4, lq = lane & 15;

    floatx4 acc[4][2] = {};
    const bf16* Ap = A + (size_t)m0 * K + (size_t)sk * Kh;
    const bf16* Bp = Bt + (size_t)n0 * K + (size_t)sk * Kh;

    for (int k0 = 0; k0 < Kh; k0 += 64) {
        stage_tile_sw<128, 64>(As, Ap + k0, K, wave, lane);
        stage_tile_sw<64, 64>(Bs, Bp + k0, K, wave, lane);
        __syncthreads();
        #pragma unroll
        for (int kk = 0; kk < 2; kk++) {
            const int chs = ((kk * 4 + quad) ^ (lq & 7)) * 8;
            bf16x8 af[4], bfr[2];
            #pragma unroll
            for (int i = 0; i < 4; i++)
                af[i] = *(const bf16x8*)&As[(wr * 64 + i * 16 + lq) * 64 + chs];
            #pragma unroll
            for (int jj = 0; jj < 2; jj++)
                bfr[jj] = *(const bf16x8*)&Bs[(wc * 32 + jj * 16 + lq) * 64 + chs];
            #pragma unroll
            for (int i = 0; i < 4; i++)
                #pragma unroll
                for (int jj = 0; jj < 2; jj++)
                    acc[i][jj] = __builtin_amdgcn_mfma_f32_16x16x32_bf16(af[i], bfr[jj], acc[i][jj], 0, 0, 0);
        }
        __syncthreads();
    }
    float* op = out + (size_t)sk * 4194304;    // partial-sum buffer for this half
    #pragma unroll
    for (int jj = 0; jj < 2; jj++) {
        const int gc = n0 + wc * 32 + jj * 16 + lq;
        const float bv = sk ? 0.f : bias[gc];
        #pragma unroll
        for (int i = 0; i < 4; i++)
            #pragma unroll
            for (int r = 0; r < 4; r++) {
                const int gr = m0 + wr * 64 + i * 16 + quad * 4 + r;
                op[(size_t)gr * 1024 + gc] = acc[i][jj][r] + bv;
            }
    }
}

// ---------------- fused per-layer weight transpose+convert ----------------
__device__ __forceinline__ void ttile(const float* __restrict__ src, bf16* __restrict__ dst,
                                      int K, int N, int n0, int k0) {
    __shared__ float t[32][33];
    const int tx = threadIdx.x & 31, ty = threadIdx.x >> 5;
    #pragma unroll
    for (int i = 0; i < 4; i++)
        t[ty + i * 8][tx] = src[(size_t)(k0 + ty + i * 8) * N + n0 + tx];
    __syncthreads();
    #pragma unroll
    for (int i = 0; i < 4; i++)
        dst[(size_t)(n0 + ty + i * 8) * K + k0 + tx] = (bf16)t[tx][ty + i * 8];
}

__global__ __launch_bounds__(256) void transpose_all(const float* Wq, const float* Wk, const float* Wv,
                                                     const float* Wo, const float* W1, const float* W2,
                                                     bf16* qkvT, bf16* oT, bf16* w1T, bf16* w2T) {
    const int bx = blockIdx.x;
    if (bx < 4096) {
        const int z = bx >> 10, tile = bx & 1023;
        const float* s = (z == 0) ? Wq : (z == 1) ? Wk : (z == 2) ? Wv : Wo;
        bf16* d = (z == 3) ? oT : qkvT + (size_t)z * 1048576;
        ttile(s, d, 1024, 1024, (tile & 31) * 32, (tile >> 5) * 32);
    } else if (bx < 8192) {
        const int tile = bx - 4096;
        ttile(W1, w1T, 1024, 4096, (tile & 127) * 32, (tile >> 7) * 32);
    } else {
        const int tile = bx - 8192;
        ttile(W2, w2T, 4096, 1024, (tile & 31) * 32, (tile >> 5) * 32);
    }
}

// v [4096, h*64+d] bf16 -> vT [bh][d][L] with per-128-L-block k-permutation:
// within each 128 block, element position l'*8+j holds the value at L = 16*j + l'.
__global__ __launch_bounds__(256) void transpose_v(const bf16* v, bf16* vT) {
    __shared__ float t[128][34];
    const int l0 = blockIdx.x * 128, d0 = blockIdx.y * 32, bh = blockIdx.z;
    const int b = bh >> 4, h = bh & 15;
    const int tid = threadIdx.x;
    const int dp = (tid & 15) * 2, lr = tid >> 4;   // lr in [0,16)
    #pragma unroll
    for (int i = 0; i < 8; i++) {
        const int lrow = lr + i * 16;
        bf16 two[2];
        *(uint32_t*)two = *(const uint32_t*)&v[(size_t)(b * 1024 + l0 + lrow) * 1024 + h * 64 + d0 + dp];
        t[lrow][dp]     = (float)two[0];
        t[lrow][dp + 1] = (float)two[1];
    }
    __syncthreads();
    #pragma unroll
    for (int u2 = 0; u2 < 2; u2++) {
        const int c = tid + u2 * 256;
        const int d = c >> 4, lp = c & 15;
        bf16 pb[8];
        #pragma unroll
        for (int j = 0; j < 8; j++)
            pb[j] = (bf16)t[j * 16 + lp][d];
        *(bf16x8*)&vT[((size_t)bh * 64 + d0 + d) * 1024 + l0 + lp * 8] = *(bf16x8*)pb;
    }
}

__global__ __launch_bounds__(256) void cvt_f32_bf16(const float* src, bf16* dst) {
    const int i = (blockIdx.x * 256 + threadIdx.x) * 4;
    const float4 v = *(const float4*)(src + i);
    bf16 t4[4] = {(bf16)v.x, (bf16)v.y, (bf16)v.z, (bf16)v.w};
    *(uint64_t*)(dst + i) = *(const uint64_t*)t4;
}

// ---------------- LayerNorm( a0 + a1 + res ) — a0/a1 are the split-K partials ----------------
__global__ __launch_bounds__(256) void ln_kernel(const float* __restrict__ a, const float* __restrict__ a2,
                                                 const float* __restrict__ res,
                                                 const float* __restrict__ gamma, const float* __restrict__ beta,
                                                 float* __restrict__ outf, bf16* __restrict__ outb) {
    const int row = blockIdx.x, tid = threadIdx.x;
    const size_t base = (size_t)row * 1024 + tid * 4;
    const float4 av  = *(const float4*)(a + base);
    const float4 a2v = *(const float4*)(a2 + base);
    const float4 rv  = *(const float4*)(res + base);
    float x0 = av.x + a2v.x + rv.x, x1 = av.y + a2v.y + rv.y;
    float x2 = av.z + a2v.z + rv.z, x3 = av.w + a2v.w + rv.w;
    float s  = x0 + x1 + x2 + x3;
    float sq = x0 * x0 + x1 * x1 + x2 * x2 + x3 * x3;
    #pragma unroll
    for (int off = 32; off; off >>= 1) {
        s  += __shfl_xor(s,  off, 64);
        sq += __shfl_xor(sq, off, 64);
    }
    __shared__ float red[8];
    const int wave = tid >> 6, lane = tid & 63;
    if (lane == 0) { red[wave] = s; red[wave + 4] = sq; }
    __syncthreads();
    const float S  = red[0] + red[1] + red[2] + red[3];
    const float SQ = red[4] + red[5] + red[6] + red[7];
    const float mean = S * (1.f / 1024.f);
    const float var  = SQ * (1.f / 1024.f) - mean * mean;
    const float rstd = rsqrtf(var + 1e-6f);
    const int c = tid * 4;
    const float4 g  = *(const float4*)(gamma + c);
    const float4 be = *(const float4*)(beta + c);
    float y0 = (x0 - mean) * rstd * g.x + be.x;
    float y1 = (x1 - mean) * rstd * g.y + be.y;
    float y2 = (x2 - mean) * rstd * g.z + be.z;
    float y3 = (x3 - mean) * rstd * g.w + be.w;
    float4 yo; yo.x = y0; yo.y = y1; yo.z = y2; yo.w = y3;
    *(float4*)(outf + base) = yo;
    bf16 t4[4] = {(bf16)y0, (bf16)y1, (bf16)y2, (bf16)y3};
    *(uint64_t*)(outb + base) = *(const uint64_t*)t4;
}

// ---------------- flash attention (R3 version, verified) ----------------
__global__ __launch_bounds__(256, 2) void attn_kernel(const bf16* __restrict__ Q, const bf16* __restrict__ Kg,
                                                      const bf16* __restrict__ Vt, bf16* __restrict__ O) {
    __shared__ bf16 Ks[128 * 64];
    __shared__ bf16 Vs[64 * 128];
    __shared__ bf16 Ps[128 * 128];
    const int bh = blockIdx.x, qt = blockIdx.y;
    const int b = bh >> 4, h = bh & 15;
    const int tid = threadIdx.x, wave = tid >> 6, lane = tid & 63;
    const int quad = lane >> 4, lq = lane & 15;

    const bf16* qg = Q + ((size_t)b * 1024 + qt * 128) * 1024 + h * 64;
    const bf16* kg = Kg + (size_t)b * 1024 * 1024 + h * 64;
    const bf16* vg = Vt + (size_t)bh * 64 * 1024;

    stage_tile_sw<128, 64>(Ps, qg, 1024, wave, lane);
    __syncthreads();
    bf16x8 aq[2][2];
    #pragma unroll
    for (int i = 0; i < 2; i++)
        #pragma unroll
        for (int kk = 0; kk < 2; kk++) {
            const int row = wave * 32 + i * 16 + lq;
            const int chs = (kk * 4 + quad) ^ (lq & 7);
            aq[i][kk] = *(const bf16x8*)&Ps[row * 64 + chs * 8];
        }

    floatx4 oacc[2][4] = {};
    float lsum[2][4] = {};

    for (int kt = 0; kt < 1024; kt += 128) {
        stage_tile_sw<128, 64>(Ks, kg + (size_t)kt * 1024, 1024, wave, lane);
        stage_tile_sw<64, 128>(Vs, vg + kt, 1024, wave, lane);
        __syncthreads();

        floatx4 sacc[2][8] = {};
        #pragma unroll
        for (int kk = 0; kk < 2; kk++)
            #pragma unroll
            for (int j = 0; j < 8; j++) {
                const int chs = (kk * 4 + quad) ^ (lq & 7);
                bf16x8 bk = *(const bf16x8*)&Ks[(j * 16 + lq) * 64 + chs * 8];
                sacc[0][j] = __builtin_amdgcn_mfma_f32_16x16x32_bf16(aq[0][kk], bk, sacc[0][j], 0, 0, 0);
                sacc[1][j] = __builtin_amdgcn_mfma_f32_16x16x32_bf16(aq[1][kk], bk, sacc[1][j], 0, 0, 0);
            }

        // softmax-exp + packed P store: one b128 per (i,r)
        #pragma unroll
        for (int i = 0; i < 2; i++)
            #pragma unroll
            for (int r = 0; r < 4; r++) {
                const int row = wave * 32 + i * 16 + quad * 4 + r;
                float ls = 0.f;
                bf16 pb[8];
                #pragma unroll
                for (int j = 0; j < 8; j++) {
                    const float pv = exp2f(sacc[i][j][r]);
                    ls += pv;
                    pb[j] = (bf16)pv;
                }
                lsum[i][r] += ls;
                *(bf16x8*)&Ps[row * 128 + (lq ^ (row & 7)) * 8] = *(const bf16x8*)pb;
            }

        #pragma unroll
        for (int kk = 0; kk < 4; kk++) {
            bf16x8 ap[2];
            #pragma unroll
            for (int i = 0; i < 2; i++) {
                const int row = wave * 32 + i * 16 + lq;
                const int chs = (kk * 4 + quad) ^ (lq & 7);
                ap[i] = *(const bf16x8*)&Ps[row * 128 + chs * 8];
            }
            #pragma unroll
            for (int dj = 0; dj < 4; dj++) {
                const int chs = (kk * 4 + quad) ^ (lq & 7);
                bf16x8 bv = *(const bf16x8*)&Vs[(dj * 16 + lq) * 128 + chs * 8];
                oacc[0][dj] = __builtin_amdgcn_mfma_f32_16x16x32_bf16(ap[0], bv, oacc[0][dj], 0, 0, 0);
                oacc[1][dj] = __builtin_amdgcn_mfma_f32_16x16x32_bf16(ap[1], bv, oacc[1][dj], 0, 0, 0);
            }
        }
        __syncthreads();
    }

    #pragma unroll
    for (int i = 0; i < 2; i++)
        #pragma unroll
        for (int r = 0; r < 4; r++) {
            float l = lsum[i][r];
            l += __shfl_xor(l, 1, 64); l += __shfl_xor(l, 2, 64);
            l += __shfl_xor(l, 4, 64); l += __shfl_xor(l, 8, 64);
            lsum[i][r] = 1.f / l;
        }
    #pragma unroll
    for (int i = 0; i < 2; i++)
        #pragma unroll
        for (int dj = 0; dj < 4; dj++)
            #pragma unroll
            for (int r = 0; r < 4; r++) {
                const int row = qt * 128 + wave * 32 + i * 16 + quad * 4 + r;
                O[((size_t)b * 1024 + row) * 1024 + h * 64 + dj * 16 + lq] = (bf16)(oacc[i][dj][r] * lsum[i][r]);
            }
}

// ---------------- host ----------------
extern "C" void kernel_launch(void* const* d_in, const int* in_sizes, int n_in,
                              void* d_out, int out_size, void* d_ws, size_t ws_size,
                              hipStream_t stream) {
    const float* queries = (const float*)d_in[0];
    const float* Wq = (const float*)d_in[1];  const float* bq = (const float*)d_in[2];
    const float* Wk = (const float*)d_in[3];  const float* bk = (const float*)d_in[4];
    const float* Wv = (const float*)d_in[5];  const float* bv = (const float*)d_in[6];
    const float* Wo = (const float*)d_in[7];  const float* bo = (const float*)d_in[8];
    const float* ln1_s = (const float*)d_in[9];   const float* ln1_b = (const float*)d_in[10];
    const float* ln2_s = (const float*)d_in[11];  const float* ln2_b = (const float*)d_in[12];
    const float* W1 = (const float*)d_in[13]; const float* b1 = (const float*)d_in[14];
    const float* W2 = (const float*)d_in[15]; const float* b2 = (const float*)d_in[16];

    char* p = (char*)d_ws;
    size_t off = 0;
    auto take = [&](size_t bytes) { void* r = p + off; off += bytes; return r; };
    bf16*  WqkvT = (bf16*)take(6291456);
    bf16*  WoT   = (bf16*)take(2097152);
    bf16*  W1T   = (bf16*)take(8388608);
    bf16*  W2T   = (bf16*)take(8388608);
    bf16*  x_bf  = (bf16*)take(8388608);
    float* xf    = (float*)take(16777216);
    bf16*  qkvb  = (bf16*)take(25165824);
    bf16*  vTb   = (bf16*)take(8388608);
    bf16*  updb  = (bf16*)take(8388608);
    float* az    = (float*)take(33554432);   // 2x f32 partials (split-K)
    float* hf    = (float*)take(16777216);
    bf16*  hbf   = (bf16*)take(8388608);
    bf16*  tmlp  = (bf16*)take(33554432);

    cvt_f32_bf16<<<4096, 256, 0, stream>>>(queries, x_bf);

    for (int l = 0; l < 4; ++l) {
        const size_t w1k = (size_t)l * 1024 * 1024;
        const size_t w4m = (size_t)l * 4096 * 1024;
        transpose_all<<<12288, 256, 0, stream>>>(Wq + w1k, Wk + w1k, Wv + w1k, Wo + w1k,
                                                 W1 + w4m, W2 + w4m, WqkvT, WoT, W1T, W2T);

        gemm_qkv<<<768, 256, 0, stream>>>(x_bf, WqkvT,
                                          bq + l * 1024, bk + l * 1024, bv + l * 1024, qkvb);
        transpose_v<<<dim3(8, 2, 64), 256, 0, stream>>>(qkvb + 2 * 4194304, vTb);
        attn_kernel<<<dim3(64, 8), 256, 0, stream>>>(qkvb, qkvb + 4194304, vTb, updb);
        gemm_n1024<<<1024, 256, 0, stream>>>(updb, WoT, bo + l * 1024, az, 1024);
        ln_kernel<<<4096, 256, 0, stream>>>(az, az + 4194304, (l == 0) ? queries : xf,
                                            ln1_s + l * 1024, ln1_b + l * 1024, hf, hbf);
        gemm_mlp1<<<256, 512, 0, stream>>>(hbf, W1T, b1 + l * 4096, tmlp);
        gemm_n1024<<<1024, 256, 0, stream>>>(tmlp, W2T, b2 + l * 1024, az, 4096);
        ln_kernel<<<4096, 256, 0, stream>>>(az, az + 4194304, hf, ln2_s + l * 1024, ln2_b + l * 1024,
                                            (l == 3) ? (float*)d_out : xf, x_bf);
    }
}